// Round 2
// baseline (71.478 us; speedup 1.0000x reference)
//
#include <hip/hip_runtime.h>
#include <math.h>

namespace {

constexpr int C  = 25;
constexpr int TP = 256;  // pairs per tile (= blockDim.x)

struct Ws {
  int    last_neg;   // offset 0
  int    pad0;
  double ce_sum;     // offset 8
  double tail_sum;   // offset 16
  float  norm_last;  // offset 24
};

__global__ void k_init(Ws* ws) {
  ws->last_neg  = -1;
  ws->ce_sum    = 0.0;
  ws->tail_sum  = 0.0;
  ws->norm_last = 0.0f;
}

// Find max pair index with labels[2p] != labels[2p+1].
__global__ __launch_bounds__(256)
void k_lastneg(const int* __restrict__ labels, int P, Ws* __restrict__ ws) {
  int best = -1;
  for (int p = blockIdx.x * blockDim.x + threadIdx.x; p < P;
       p += gridDim.x * blockDim.x) {
    int2 l = reinterpret_cast<const int2*>(labels)[p];
    if (l.x != l.y) best = p;  // p increases monotonically per thread
  }
#pragma unroll
  for (int off = 32; off; off >>= 1)
    best = max(best, __shfl_down(best, off, 64));
  __shared__ int smax[4];
  const int lane = threadIdx.x & 63, wid = threadIdx.x >> 6;
  if (lane == 0) smax[wid] = best;
  __syncthreads();
  if (threadIdx.x == 0) {
    int b = max(max(smax[0], smax[1]), max(smax[2], smax[3]));
    atomicMax(&ws->last_neg, b);
  }
}

// Main fused pass: LDS-staged tiles of TP pairs; one thread per pair.
__global__ __launch_bounds__(256)
void k_main(const float* __restrict__ x, const int* __restrict__ labels,
            const float* __restrict__ M, int P, Ws* __restrict__ ws) {
  __shared__ float colsq[C];
  __shared__ float tile[TP * 2 * C];  // 256*50*4 = 51200 B, linear (no pad)

  const int t = threadIdx.x;
  if (t < C) {
    float s = 0.f;
    for (int r = 0; r < C; ++r) {
      float m = M[r * C + t];
      s += m * m;
    }
    colsq[t] = s;
  }

  const int last_neg = ws->last_neg;

  float  ce_local   = 0.f;
  double tail_local = 0.0;

  const int ntiles = (P + TP - 1) / TP;
  for (int ti = blockIdx.x; ti < ntiles; ti += gridDim.x) {
    const int pair0  = ti * TP;
    const int npairs = min(TP, P - pair0);
    const size_t fbase = (size_t)pair0 * (2 * C);

    // ---- stage: coalesced float4 global loads -> lane-linear LDS b128 ----
    if (npairs == TP) {
      const float4* g4 = reinterpret_cast<const float4*>(x + fbase);
      float4* t4 = reinterpret_cast<float4*>(tile);
#pragma unroll
      for (int k = 0; k < 13; ++k) {
        int i = t + k * 256;
        if (i < TP * 2 * C / 4) t4[i] = g4[i];
      }
    } else {
      for (int f = t; f < npairs * 2 * C; f += 256) tile[f] = x[fbase + f];
    }
    __syncthreads();

    // ---- compute: one thread per pair ----
    if (t < npairs) {
      const int p = pair0 + t;
      const int2 l = reinterpret_cast<const int2*>(labels)[p];
      const float* e = &tile[t * (2 * C)];

      float er[2 * C];
#pragma unroll
      for (int c = 0; c < 2 * C; ++c) er[c] = e[c];

      float ma = -INFINITY, mb = -INFINITY;
#pragma unroll
      for (int c = 0; c < C; ++c) {
        ma = fmaxf(ma, er[c]);
        mb = fmaxf(mb, er[C + c]);
      }
      float sa = 0.f, sb = 0.f;
#pragma unroll
      for (int c = 0; c < C; ++c) {
        sa += __expf(er[c] - ma);
        sb += __expf(er[C + c] - mb);
      }
      const float lse_a = ma + __logf(sa);
      const float lse_b = mb + __logf(sb);
      const float xa = e[l.x];       // dynamic LDS index — cheap & legal
      const float xb = e[C + l.y];
      ce_local += (lse_a - xa) + (lse_b - xb);

      if (l.x == l.y) {
        if (p > last_neg) {
          float s = 0.f;
#pragma unroll
          for (int c = 0; c < C; ++c) {
            float d = er[c] - er[C + c];
            s = fmaf(d * d, colsq[c], s);
          }
          tail_local += (double)sqrtf(s);
        }
      } else if (p == last_neg) {
        float s = 0.f;
#pragma unroll
        for (int c = 0; c < C; ++c) {
          float d = er[c] - er[C + c];
          s = fmaf(d * d, colsq[c], s);
        }
        ws->norm_last = sqrtf(s);
      }
    }
    __syncthreads();
  }

  // block-reduce ce (float within block, double atomic across blocks)
#pragma unroll
  for (int off = 32; off; off >>= 1)
    ce_local += __shfl_down(ce_local, off, 64);
  __shared__ float wce[4];
  const int lane = threadIdx.x & 63, wid = threadIdx.x >> 6;
  if (lane == 0) wce[wid] = ce_local;
  __syncthreads();
  if (threadIdx.x == 0) {
    float bs = (wce[0] + wce[1]) + (wce[2] + wce[3]);
    atomicAdd(&ws->ce_sum, (double)bs);
  }
  if (tail_local != 0.0) atomicAdd(&ws->tail_sum, tail_local);
}

__global__ void k_fin(const Ws* __restrict__ ws, float* __restrict__ out,
                      float invB) {
  double ce = ws->ce_sum * (double)invB;
  float ml = 1.0f + (float)ws->tail_sum - ws->norm_last;
  ml = fmaxf(ml, 0.0f);
  out[0] = (float)(ce + 0.005 * (double)ml);
}

}  // namespace

extern "C" void kernel_launch(void* const* d_in, const int* in_sizes, int n_in,
                              void* d_out, int out_size, void* d_ws,
                              size_t ws_size, hipStream_t stream) {
  const float* x      = (const float*)d_in[0];
  const int*   labels = (const int*)d_in[1];
  const float* M      = (const float*)d_in[2];
  float*       out    = (float*)d_out;
  Ws*          ws     = (Ws*)d_ws;

  const int B = in_sizes[1];
  const int P = B / 2;

  k_init<<<1, 1, 0, stream>>>(ws);
  k_lastneg<<<1024, 256, 0, stream>>>(labels, P, ws);
  k_main<<<2048, 256, 0, stream>>>(x, labels, M, P, ws);
  k_fin<<<1, 1, 0, stream>>>(ws, out, 1.0f / (float)B);
}

// Round 3
// 65.160 us; speedup vs baseline: 1.0970x; 1.0970x over previous
//
#include <hip/hip_runtime.h>
#include <math.h>

namespace {

constexpr int C = 25;

struct Ws {
  int    last_neg;   // offset 0
  int    pad0;
  double ce_sum;     // offset 8
};

__global__ void k_init(Ws* ws) {
  ws->last_neg = -1;
  ws->ce_sum   = 0.0;
}

// Find max pair index with labels[2p] != labels[2p+1].
__global__ __launch_bounds__(256)
void k_lastneg(const int* __restrict__ labels, int P, Ws* __restrict__ ws) {
  int best = -1;
  for (int p = blockIdx.x * blockDim.x + threadIdx.x; p < P;
       p += gridDim.x * blockDim.x) {
    int2 l = reinterpret_cast<const int2*>(labels)[p];
    if (l.x != l.y) best = p;  // p increases monotonically per thread
  }
#pragma unroll
  for (int off = 32; off; off >>= 1)
    best = max(best, __shfl_down(best, off, 64));
  __shared__ int smax[4];
  const int lane = threadIdx.x & 63, wid = threadIdx.x >> 6;
  if (lane == 0) smax[wid] = best;
  __syncthreads();
  if (threadIdx.x == 0) {
    int b = max(max(smax[0], smax[1]), max(smax[2], smax[3]));
    atomicMax(&ws->last_neg, b);
  }
}

// Pure cross-entropy pass: one thread per 4 consecutive rows (400 B,
// 16B-aligned) -> 25 x float4 loads = 16 B per TA address.
__global__ __launch_bounds__(256)
void k_ce(const float* __restrict__ x, const int* __restrict__ labels,
          int B, Ws* __restrict__ ws) {
  const int Q = B >> 2;  // number of row-quads
  float ce_local = 0.f;

  for (int q = blockIdx.x * blockDim.x + threadIdx.x; q < Q;
       q += gridDim.x * blockDim.x) {
    const float4* g4 = reinterpret_cast<const float4*>(x + (size_t)q * 100);
    float e[100];
#pragma unroll
    for (int j = 0; j < 25; ++j) {
      float4 v = g4[j];
      e[4 * j + 0] = v.x;
      e[4 * j + 1] = v.y;
      e[4 * j + 2] = v.z;
      e[4 * j + 3] = v.w;
    }
    const int4 lb = reinterpret_cast<const int4*>(labels)[q];
    const int l[4] = {lb.x, lb.y, lb.z, lb.w};

#pragma unroll
    for (int r = 0; r < 4; ++r) {
      float m = e[r * 25];
#pragma unroll
      for (int c = 1; c < C; ++c) m = fmaxf(m, e[r * 25 + c]);
      float s = 0.f, xl = 0.f;
      const int lr = l[r];
#pragma unroll
      for (int c = 0; c < C; ++c) {
        const float v = e[r * 25 + c];
        s += __expf(v - m);
        xl = (c == lr) ? v : xl;  // in-register label select (static idx)
      }
      ce_local += (m + __logf(s)) - xl;
    }
  }

  // block-reduce (float within block, double atomic across blocks)
#pragma unroll
  for (int off = 32; off; off >>= 1)
    ce_local += __shfl_down(ce_local, off, 64);
  __shared__ float wce[4];
  const int lane = threadIdx.x & 63, wid = threadIdx.x >> 6;
  if (lane == 0) wce[wid] = ce_local;
  __syncthreads();
  if (threadIdx.x == 0) {
    float bs = (wce[0] + wce[1]) + (wce[2] + wce[3]);
    atomicAdd(&ws->ce_sum, (double)bs);
  }
}

// Finalize: metric tail (pairs > last_neg are all same-label and form a tiny
// suffix for random labels) + norm at last_neg + combine with CE. One block.
__global__ __launch_bounds__(256)
void k_fin(const float* __restrict__ x, const int* __restrict__ labels,
           const float* __restrict__ M, int P, const Ws* __restrict__ ws,
           float* __restrict__ out, float invB) {
  __shared__ float colsq[C];
  __shared__ double ssum[4];
  __shared__ float snorm;
  const int t = threadIdx.x;
  if (t < C) {
    float s = 0.f;
    for (int r = 0; r < C; ++r) {
      float m = M[r * C + t];
      s += m * m;
    }
    colsq[t] = s;
  }
  if (t == 0) snorm = 0.f;
  __syncthreads();

  const int last_neg = ws->last_neg;

  double tail = 0.0;
  // pairs strictly after last_neg (all same-label by construction of last_neg)
  for (int p = last_neg + 1 + t; p < P; p += blockDim.x) {
    const float* e = x + (size_t)p * (2 * C);
    float s = 0.f;
#pragma unroll
    for (int c = 0; c < C; ++c) {
      float d = e[c] - e[C + c];
      s = fmaf(d * d, colsq[c], s);
    }
    tail += (double)sqrtf(s);
  }
  if (t == 0 && last_neg >= 0) {
    const float* e = x + (size_t)last_neg * (2 * C);
    float s = 0.f;
#pragma unroll
    for (int c = 0; c < C; ++c) {
      float d = e[c] - e[C + c];
      s = fmaf(d * d, colsq[c], s);
    }
    snorm = sqrtf(s);
  }

  // reduce tail across the block
#pragma unroll
  for (int off = 32; off; off >>= 1)
    tail += __shfl_down(tail, off, 64);
  const int lane = t & 63, wid = t >> 6;
  if (lane == 0) ssum[wid] = tail;
  __syncthreads();
  if (t == 0) {
    double tl = (ssum[0] + ssum[1]) + (ssum[2] + ssum[3]);
    double ce = ws->ce_sum * (double)invB;
    float ml = fmaxf(1.0f + (float)tl - snorm, 0.0f);
    out[0] = (float)(ce + 0.005 * (double)ml);
  }
}

}  // namespace

extern "C" void kernel_launch(void* const* d_in, const int* in_sizes, int n_in,
                              void* d_out, int out_size, void* d_ws,
                              size_t ws_size, hipStream_t stream) {
  const float* x      = (const float*)d_in[0];
  const int*   labels = (const int*)d_in[1];
  const float* M      = (const float*)d_in[2];
  float*       out    = (float*)d_out;
  Ws*          ws     = (Ws*)d_ws;

  const int B = in_sizes[1];
  const int P = B / 2;

  k_init<<<1, 1, 0, stream>>>(ws);
  k_lastneg<<<1024, 256, 0, stream>>>(labels, P, ws);
  k_ce<<<2048, 256, 0, stream>>>(x, labels, B, ws);
  k_fin<<<1, 256, 0, stream>>>(x, labels, M, P, ws, out, 1.0f / (float)B);
}